// Round 1
// baseline (1700.997 us; speedup 1.0000x reference)
//
#include <hip/hip_runtime.h>

#define Bsz 128
#define Tn  1024
#define Dn  256
#define Hn  256

typedef _Float16 f16;
typedef _Float16 f16x4 __attribute__((ext_vector_type(4)));
typedef _Float16 f16x8 __attribute__((ext_vector_type(8)));
typedef float f32x4 __attribute__((ext_vector_type(4)));

// Exact tanh: 1 - 2/(e^{2x}+1) via v_exp_f32. err ~1e-6, saturates correctly.
__device__ __forceinline__ float tanh_fast(float x) {
    float e = __builtin_amdgcn_exp2f(x * 2.88539008177793f);  // e^{2x}
    return 1.0f - 2.0f * __builtin_amdgcn_rcpf(e + 1.0f);
}

// LDS-only barrier (lgkmcnt drain, no vmcnt) so global prefetch loads stay
// in flight across steps. All global loads are consumed by the issuing lane.
__device__ __forceinline__ void wg_barrier() {
    asm volatile("s_waitcnt lgkmcnt(0)\n\ts_barrier" ::: "memory");
}

// h fragment-major LDS layout: element (m=batch 0..15, k=0..255) lives at
// f16 offset (k>>5)*512 + ((k>>3)&3)*128 + m*8 + (k&7).
// A wave's B-fragment read for K-block kk is then ds_read_b128 at
// kk*1024B + lane*16B  -> stride-1 lane-contiguous, conflict-free.

// ---------------------------------------------------------------------------
// K1: pre_T[t][j][b] = x[b][t][:] . Wxh0[j][:] + b0[j]   (fp32 in/out)
// Transposed GEMM: A = Wxh0 (j rows, regs), B = x_t (b cols, LDS).
// grid = Tn WGs (one t each), 256 thr (4 waves x 64 j-cols).   [UNCHANGED]
// ---------------------------------------------------------------------------
__global__ __launch_bounds__(256, 2) void k_xproj(
    const float* __restrict__ x, const float* __restrict__ W,
    const float* __restrict__ bias, float* __restrict__ preT)
{
    __shared__ __align__(16) f16 xt[128][264];
    const int tid = threadIdx.x;
    const int t = blockIdx.x;

    // stage x[:, t, :] -> f16 LDS (row-major, padded)
    for (int i = tid; i < 128 * 64; i += 256) {
        int row = i >> 6, c4 = i & 63;
        float4 v = *(const float4*)(x + ((size_t)row * Tn + t) * Dn + c4 * 4);
        f16x4 tv = { (f16)v.x, (f16)v.y, (f16)v.z, (f16)v.w };
        *(f16x4*)(&xt[row][c4 * 4]) = tv;
    }

    const int lane = tid & 63, l15 = lane & 15, quad = lane >> 4;
    const int w = tid >> 6;

    // A-fragments of Wxh0 (j = w*64 + jn*16 + l15, k = kk*32 + quad*8 + e)
    f16x8 wf[4][8];
    #pragma unroll
    for (int jn = 0; jn < 4; jn++) {
        int j = w * 64 + jn * 16 + l15;
        #pragma unroll
        for (int kk = 0; kk < 8; kk++)
            #pragma unroll
            for (int e = 0; e < 8; e++)
                wf[jn][kk][e] = (f16)W[(size_t)j * Dn + kk * 32 + quad * 8 + e];
    }
    float4 bi[4];
    #pragma unroll
    for (int jn = 0; jn < 4; jn++)
        bi[jn] = *(const float4*)(bias + w * 64 + jn * 16 + quad * 4);

    __syncthreads();

    #pragma unroll 1
    for (int bblk = 0; bblk < 8; bblk++) {
        f32x4 acc[4];
        #pragma unroll
        for (int jn = 0; jn < 4; jn++)
            acc[jn] = (f32x4){bi[jn].x, bi[jn].y, bi[jn].z, bi[jn].w};
        #pragma unroll
        for (int kk = 0; kk < 8; kk++) {
            f16x8 xb = *(const f16x8*)(&xt[bblk * 16 + l15][kk * 32 + quad * 8]);
            #pragma unroll
            for (int jn = 0; jn < 4; jn++)
                acc[jn] = __builtin_amdgcn_mfma_f32_16x16x32_f16(wf[jn][kk], xb, acc[jn], 0, 0, 0);
        }
        // C-layout: lane holds rows j = w*64+jn*16+quad*4+r, col b = bblk*16+l15
        #pragma unroll
        for (int jn = 0; jn < 4; jn++)
            #pragma unroll
            for (int r = 0; r < 4; r++) {
                int j = w * 64 + jn * 16 + quad * 4 + r;
                preT[((size_t)t * Hn + j) * Bsz + bblk * 16 + l15] = acc[jn][r];
            }
    }
}

// ---------------------------------------------------------------------------
// K2 (fused, LAYER-PIPELINED): layer 2 lags layer 1 by one step so each
// iteration i does, per wave (32 j-cols of BOTH layers), with ONE barrier:
//   h1[i]   = tanh(pre[i] + Whh0 . h1[i-1])                (accA, 2x8 chain)
//   h2[i-1] = tanh(b1 + Wxh1 . h1[i-1] + Whh1 . h2[i-2])   (accX+accH, 4x8)
// Both consume h1[i-1] (written before last barrier) -> shared ds_read, and
// 6 independent 8-deep MFMA chains keep the per-CU matrix pipe fed.
// 1025 iterations; i=0 suppresses the h2 write (preserves h2[-1]=0),
// i=Tn suppresses the h1 write. Parity: h1[i] in h1f[i&1], h2[i] in h2f[i&1].
// 8 WGs x 512 thr; weights (Whh0, Wxh1, Whh1) as A-fragments in registers.
// ---------------------------------------------------------------------------
__global__ __launch_bounds__(512, 1) void k_fused(
    const float* __restrict__ Whh0, const float* __restrict__ Wxh1,
    const float* __restrict__ Whh1, const float* __restrict__ b1v,
    const float* __restrict__ fcw,  const float* __restrict__ fcb,
    const float* __restrict__ preT, float* __restrict__ out)
{
    __shared__ __align__(16) f16 h1f[2][4096];  // 8 KB each, frag-major
    __shared__ __align__(16) f16 h2f[2][4096];

    const int tid  = threadIdx.x;
    const int lane = tid & 63, l15 = lane & 15, quad = lane >> 4;
    const int w    = tid >> 6;
    const int colbase = w * 32;
    const int bg   = blockIdx.x * 16;

    for (int i = tid; i < 4096; i += 512) {
        h1f[0][i] = (f16)0.0f; h1f[1][i] = (f16)0.0f;
        h2f[0][i] = (f16)0.0f; h2f[1][i] = (f16)0.0f;
    }

    // A-fragments: row j = colbase + jn*16 + l15, k = kk*32 + quad*8 + e
    f16x8 wh0[2][8], wx[2][8], wh1[2][8];
    #pragma unroll
    for (int jn = 0; jn < 2; jn++) {
        int j = colbase + jn * 16 + l15;
        #pragma unroll
        for (int kk = 0; kk < 8; kk++)
            #pragma unroll
            for (int e = 0; e < 8; e++) {
                int o = (int)((size_t)j * Hn + kk * 32 + quad * 8 + e);
                wh0[jn][kk][e] = (f16)Whh0[o];
                wx [jn][kk][e] = (f16)Wxh1[o];
                wh1[jn][kk][e] = (f16)Whh1[o];
            }
    }
    float4 bi[2];
    #pragma unroll
    for (int jn = 0; jn < 2; jn++)
        bi[jn] = *(const float4*)(b1v + colbase + jn * 16 + quad * 4);

    // write offsets for the h epilogue (per jn): 4 consecutive k = n0..n0+3
    int wroff[2];
    #pragma unroll
    for (int jn = 0; jn < 2; jn++) {
        int n0 = colbase + jn * 16 + quad * 4;
        wroff[jn] = (n0 >> 5) * 512 + ((n0 >> 3) & 3) * 128 + l15 * 8 + (n0 & 7);
    }

    // pre prefetch (1 step ahead): lane value (jn,r) <-> pre_T[t][j][bg+l15]
    float pn[8];
    #pragma unroll
    for (int jn = 0; jn < 2; jn++)
        #pragma unroll
        for (int r = 0; r < 4; r++) {
            int j = colbase + jn * 16 + quad * 4 + r;
            pn[jn * 4 + r] = preT[((size_t)0 * Hn + j) * Bsz + bg + l15];
        }
    __syncthreads();

// One pipelined step. PR = I&1 (compile-time). Reads h1[i-1] from h1f[PR^1],
// h2[i-2] from h2f[PR]; writes h1[i] -> h1f[PR], h2[i-1] -> h2f[PR^1].
#define FSTEP(PR, I) { \
    f32x4 accA[2], accX[2], accH[2]; \
    _Pragma("unroll") for (int jn = 0; jn < 2; jn++) { \
        _Pragma("unroll") for (int r = 0; r < 4; r++) accA[jn][r] = pn[jn*4+r]; \
        accX[jn] = (f32x4){bi[jn].x, bi[jn].y, bi[jn].z, bi[jn].w}; \
        accH[jn] = (f32x4){0.f, 0.f, 0.f, 0.f}; \
    } \
    { int tf = ((I) + 1 < Tn) ? (I) + 1 : Tn - 1; \
      _Pragma("unroll") for (int jn = 0; jn < 2; jn++) \
          _Pragma("unroll") for (int r = 0; r < 4; r++) { \
              int j = colbase + jn * 16 + quad * 4 + r; \
              pn[jn*4+r] = preT[((size_t)tf * Hn + j) * Bsz + bg + l15]; } } \
    _Pragma("unroll") for (int kk = 0; kk < 8; kk++) { \
        f16x8 hb1 = *(const f16x8*)(&h1f[(PR)^1][kk * 512 + lane * 8]); \
        f16x8 hb2 = *(const f16x8*)(&h2f[(PR)  ][kk * 512 + lane * 8]); \
        accA[0] = __builtin_amdgcn_mfma_f32_16x16x32_f16(wh0[0][kk], hb1, accA[0], 0, 0, 0); \
        accA[1] = __builtin_amdgcn_mfma_f32_16x16x32_f16(wh0[1][kk], hb1, accA[1], 0, 0, 0); \
        accX[0] = __builtin_amdgcn_mfma_f32_16x16x32_f16(wx [0][kk], hb1, accX[0], 0, 0, 0); \
        accX[1] = __builtin_amdgcn_mfma_f32_16x16x32_f16(wx [1][kk], hb1, accX[1], 0, 0, 0); \
        accH[0] = __builtin_amdgcn_mfma_f32_16x16x32_f16(wh1[0][kk], hb2, accH[0], 0, 0, 0); \
        accH[1] = __builtin_amdgcn_mfma_f32_16x16x32_f16(wh1[1][kk], hb2, accH[1], 0, 0, 0); \
    } \
    if ((I) < Tn) { \
        _Pragma("unroll") for (int jn = 0; jn < 2; jn++) { \
            f16x4 t4 = { (f16)tanh_fast(accA[jn][0]), (f16)tanh_fast(accA[jn][1]), \
                         (f16)tanh_fast(accA[jn][2]), (f16)tanh_fast(accA[jn][3]) }; \
            *(f16x4*)(&h1f[(PR)][wroff[jn]]) = t4; \
        } \
    } \
    if ((I) > 0) { \
        _Pragma("unroll") for (int jn = 0; jn < 2; jn++) { \
            f16x4 t4 = { (f16)tanh_fast(accX[jn][0] + accH[jn][0]), \
                         (f16)tanh_fast(accX[jn][1] + accH[jn][1]), \
                         (f16)tanh_fast(accX[jn][2] + accH[jn][2]), \
                         (f16)tanh_fast(accX[jn][3] + accH[jn][3]) }; \
            *(f16x4*)(&h2f[(PR)^1][wroff[jn]]) = t4; \
        } \
    } \
    wg_barrier(); \
}

    FSTEP(0, 0)                      // i = 0: h1[0] only (h2 write suppressed)
    #pragma unroll 1
    for (int tp = 0; tp < Tn / 2; ++tp) {
        const int i1 = 2 * tp + 1;   // i = 1,3,...,1023
        FSTEP(1, i1)
        FSTEP(0, (i1 + 1))           // last iter: i = 1024, h1 write suppressed
    }
#undef FSTEP

    // head: final h2 = h2[1023], parity 1023&1 = 1 -> h2f[1]; frag-major.
    if (tid < 256) {
        const int bl = tid >> 4, o = (tid >> 3) & 1, kc = tid & 7;
        float s = 0.f;
        #pragma unroll
        for (int kq = 0; kq < 32; kq++) {
            int k = kc * 32 + kq;
            f16 hv = h2f[1][(k >> 5) * 512 + ((k >> 3) & 3) * 128 + bl * 8 + (k & 7)];
            s += (float)hv * fcw[o * Hn + k];
        }
        s += __shfl_down(s, 4);
        s += __shfl_down(s, 2);
        s += __shfl_down(s, 1);
        if (kc == 0)
            out[(bg + bl) * 2 + o] = s + fcb[o];
    }
}

extern "C" void kernel_launch(void* const* d_in, const int* in_sizes, int n_in,
                              void* d_out, int out_size, void* d_ws, size_t ws_size,
                              hipStream_t stream) {
    const float* x    = (const float*)d_in[0];
    const float* Wxh0 = (const float*)d_in[1];
    const float* Whh0 = (const float*)d_in[2];
    const float* b0   = (const float*)d_in[3];
    const float* Wxh1 = (const float*)d_in[4];
    const float* Whh1 = (const float*)d_in[5];
    const float* b1   = (const float*)d_in[6];
    const float* fcw  = (const float*)d_in[7];
    const float* fcb  = (const float*)d_in[8];
    float* out = (float*)d_out;

    float* preT = (float*)d_ws;  // pre_T[t][j][b] fp32 = 128 MiB

    k_xproj<<<dim3(Tn),       dim3(256), 0, stream>>>(x, Wxh0, b0, preT);
    k_fused<<<dim3(Bsz / 16), dim3(512), 0, stream>>>(Whh0, Wxh1, Whh1, b1,
                                                      fcw, fcb, preT, out);
}

// Round 2
// 1437.847 us; speedup vs baseline: 1.1830x; 1.1830x over previous
//
#include <hip/hip_runtime.h>

#define Bsz 128
#define Tn  1024
#define Dn  256
#define Hn  256

typedef _Float16 f16;
typedef _Float16 f16x4 __attribute__((ext_vector_type(4)));
typedef _Float16 f16x8 __attribute__((ext_vector_type(8)));
typedef float f32x4 __attribute__((ext_vector_type(4)));

// Exact tanh: 1 - 2/(e^{2x}+1) via v_exp_f32. err ~1e-6, saturates correctly.
__device__ __forceinline__ float tanh_fast(float x) {
    float e = __builtin_amdgcn_exp2f(x * 2.88539008177793f);  // e^{2x}
    return 1.0f - 2.0f * __builtin_amdgcn_rcpf(e + 1.0f);
}

// LDS-only barrier (lgkmcnt drain, no vmcnt) so global prefetch loads stay
// in flight across steps. All global loads are consumed by the issuing lane.
__device__ __forceinline__ void wg_barrier() {
    asm volatile("s_waitcnt lgkmcnt(0)\n\ts_barrier" ::: "memory");
}

// h fragment-major LDS layout: element (m=batch 0..15, k=0..255) lives at
// f16 offset (k>>5)*512 + ((k>>3)&3)*128 + m*8 + (k&7).
// A wave's B-fragment read for K-block kk is then ds_read_b128 at
// kk*1024B + lane*16B  -> stride-1 lane-contiguous, conflict-free.

// ---------------------------------------------------------------------------
// K1: pre_T[t][j][b] = x[b][t][:] . Wxh0[j][:] + b0[j]   (fp32 in/out)
// Transposed GEMM: A = Wxh0 (j rows, regs), B = x_t (b cols, LDS).
// grid = Tn WGs (one t each), 256 thr (4 waves x 64 j-cols).   [UNCHANGED]
// ---------------------------------------------------------------------------
__global__ __launch_bounds__(256, 2) void k_xproj(
    const float* __restrict__ x, const float* __restrict__ W,
    const float* __restrict__ bias, float* __restrict__ preT)
{
    __shared__ __align__(16) f16 xt[128][264];
    const int tid = threadIdx.x;
    const int t = blockIdx.x;

    // stage x[:, t, :] -> f16 LDS (row-major, padded)
    for (int i = tid; i < 128 * 64; i += 256) {
        int row = i >> 6, c4 = i & 63;
        float4 v = *(const float4*)(x + ((size_t)row * Tn + t) * Dn + c4 * 4);
        f16x4 tv = { (f16)v.x, (f16)v.y, (f16)v.z, (f16)v.w };
        *(f16x4*)(&xt[row][c4 * 4]) = tv;
    }

    const int lane = tid & 63, l15 = lane & 15, quad = lane >> 4;
    const int w = tid >> 6;

    // A-fragments of Wxh0 (j = w*64 + jn*16 + l15, k = kk*32 + quad*8 + e)
    f16x8 wf[4][8];
    #pragma unroll
    for (int jn = 0; jn < 4; jn++) {
        int j = w * 64 + jn * 16 + l15;
        #pragma unroll
        for (int kk = 0; kk < 8; kk++)
            #pragma unroll
            for (int e = 0; e < 8; e++)
                wf[jn][kk][e] = (f16)W[(size_t)j * Dn + kk * 32 + quad * 8 + e];
    }
    float4 bi[4];
    #pragma unroll
    for (int jn = 0; jn < 4; jn++)
        bi[jn] = *(const float4*)(bias + w * 64 + jn * 16 + quad * 4);

    __syncthreads();

    #pragma unroll 1
    for (int bblk = 0; bblk < 8; bblk++) {
        f32x4 acc[4];
        #pragma unroll
        for (int jn = 0; jn < 4; jn++)
            acc[jn] = (f32x4){bi[jn].x, bi[jn].y, bi[jn].z, bi[jn].w};
        #pragma unroll
        for (int kk = 0; kk < 8; kk++) {
            f16x8 xb = *(const f16x8*)(&xt[bblk * 16 + l15][kk * 32 + quad * 8]);
            #pragma unroll
            for (int jn = 0; jn < 4; jn++)
                acc[jn] = __builtin_amdgcn_mfma_f32_16x16x32_f16(wf[jn][kk], xb, acc[jn], 0, 0, 0);
        }
        // C-layout: lane holds rows j = w*64+jn*16+quad*4+r, col b = bblk*16+l15
        #pragma unroll
        for (int jn = 0; jn < 4; jn++)
            #pragma unroll
            for (int r = 0; r < 4; r++) {
                int j = w * 64 + jn * 16 + quad * 4 + r;
                preT[((size_t)t * Hn + j) * Bsz + bblk * 16 + l15] = acc[jn][r];
            }
    }
}

// ---------------------------------------------------------------------------
// K2 (fused, LAYER-PIPELINED, branch-free loop): layer 2 lags layer 1 by one
// step; each iteration i does, per wave (32 j-cols of BOTH layers), with ONE
// barrier:
//   h1[i]   = tanh(pre[i] + Whh0 . h1[i-1])                  (accA, 2x 8-deep)
//   h2[i-1] = tanh(b1 + Wxh1 . h1[i-1] + Whh1 . h2[i-2])     (accB, 2x 16-deep)
// Both consume h1[i-1] (written before last barrier) -> shared ds_read; 4
// independent MFMA chains per wave keep the matrix pipe fed.
// i=0 / i=1023 / i=1024 are PEELED so the steady-state loop (i=1..1022) has
// no conditionals -> regalloc keeps the 3 weight matrices resident (r1's
// in-loop branches caused scratch spills: WRITE_SIZE 65KB -> 3.2MB).
// Parity: h1[i] in h1f[i&1], h2[i] in h2f[i&1].
// 8 WGs x 512 thr; weights (Whh0, Wxh1, Whh1) as A-fragments in registers.
// ---------------------------------------------------------------------------
__global__ __launch_bounds__(512, 1) void k_fused(
    const float* __restrict__ Whh0, const float* __restrict__ Wxh1,
    const float* __restrict__ Whh1, const float* __restrict__ b1v,
    const float* __restrict__ fcw,  const float* __restrict__ fcb,
    const float* __restrict__ preT, float* __restrict__ out)
{
    __shared__ __align__(16) f16 h1f[2][4096];  // 8 KB each, frag-major
    __shared__ __align__(16) f16 h2f[2][4096];

    const int tid  = threadIdx.x;
    const int lane = tid & 63, l15 = lane & 15, quad = lane >> 4;
    const int w    = tid >> 6;
    const int colbase = w * 32;
    const int bg   = blockIdx.x * 16;

    for (int i = tid; i < 4096; i += 512) {
        h1f[0][i] = (f16)0.0f; h1f[1][i] = (f16)0.0f;
        h2f[0][i] = (f16)0.0f; h2f[1][i] = (f16)0.0f;
    }

    // A-fragments: row j = colbase + jn*16 + l15, k = kk*32 + quad*8 + e
    f16x8 wh0[2][8], wx[2][8], wh1[2][8];
    #pragma unroll
    for (int jn = 0; jn < 2; jn++) {
        int j = colbase + jn * 16 + l15;
        #pragma unroll
        for (int kk = 0; kk < 8; kk++)
            #pragma unroll
            for (int e = 0; e < 8; e++) {
                int o = (int)((size_t)j * Hn + kk * 32 + quad * 8 + e);
                wh0[jn][kk][e] = (f16)Whh0[o];
                wx [jn][kk][e] = (f16)Wxh1[o];
                wh1[jn][kk][e] = (f16)Whh1[o];
            }
    }
    float4 bi[2];
    #pragma unroll
    for (int jn = 0; jn < 2; jn++)
        bi[jn] = *(const float4*)(b1v + colbase + jn * 16 + quad * 4);

    // write offsets for the h epilogue (per jn): 4 consecutive k = n0..n0+3
    int wroff[2];
    // prefetch base (per jn): preT element [t][j=n0+r][bg+l15] = t*Hn*Bsz +
    // pbase[jn] + r*Bsz
    int pbase[2];
    #pragma unroll
    for (int jn = 0; jn < 2; jn++) {
        int n0 = colbase + jn * 16 + quad * 4;
        wroff[jn] = (n0 >> 5) * 512 + ((n0 >> 3) & 3) * 128 + l15 * 8 + (n0 & 7);
        pbase[jn] = n0 * Bsz + bg + l15;
    }

    // pre prefetch (1 step ahead): pn holds pre[t] at entry to step t
    float pn[8];
    #pragma unroll
    for (int jn = 0; jn < 2; jn++)
        #pragma unroll
        for (int r = 0; r < 4; r++)
            pn[jn * 4 + r] = preT[pbase[jn] + r * Bsz];
    __syncthreads();

// Steady-state pipelined step, NO branches. PR = I&1 (compile-time).
// Reads h1[i-1] from h1f[PR^1], h2[i-2] from h2f[PR];
// writes h1[i] -> h1f[PR], h2[i-1] -> h2f[PR^1]. Prefetches pre[TF].
#define FSTEP_FULL(PR, I, TF) { \
    f32x4 accA[2], accB[2]; \
    _Pragma("unroll") for (int jn = 0; jn < 2; jn++) { \
        _Pragma("unroll") for (int r = 0; r < 4; r++) accA[jn][r] = pn[jn*4+r]; \
        accB[jn] = (f32x4){bi[jn].x, bi[jn].y, bi[jn].z, bi[jn].w}; \
    } \
    _Pragma("unroll") for (int jn = 0; jn < 2; jn++) \
        _Pragma("unroll") for (int r = 0; r < 4; r++) \
            pn[jn*4+r] = preT[(size_t)(TF) * (Hn * Bsz) + pbase[jn] + r * Bsz]; \
    _Pragma("unroll") for (int kk = 0; kk < 8; kk++) { \
        f16x8 hb1 = *(const f16x8*)(&h1f[(PR)^1][kk * 512 + lane * 8]); \
        f16x8 hb2 = *(const f16x8*)(&h2f[(PR)  ][kk * 512 + lane * 8]); \
        accA[0] = __builtin_amdgcn_mfma_f32_16x16x32_f16(wh0[0][kk], hb1, accA[0], 0, 0, 0); \
        accA[1] = __builtin_amdgcn_mfma_f32_16x16x32_f16(wh0[1][kk], hb1, accA[1], 0, 0, 0); \
        accB[0] = __builtin_amdgcn_mfma_f32_16x16x32_f16(wx [0][kk], hb1, accB[0], 0, 0, 0); \
        accB[1] = __builtin_amdgcn_mfma_f32_16x16x32_f16(wx [1][kk], hb1, accB[1], 0, 0, 0); \
        accB[0] = __builtin_amdgcn_mfma_f32_16x16x32_f16(wh1[0][kk], hb2, accB[0], 0, 0, 0); \
        accB[1] = __builtin_amdgcn_mfma_f32_16x16x32_f16(wh1[1][kk], hb2, accB[1], 0, 0, 0); \
    } \
    _Pragma("unroll") for (int jn = 0; jn < 2; jn++) { \
        f16x4 t1v = { (f16)tanh_fast(accA[jn][0]), (f16)tanh_fast(accA[jn][1]), \
                      (f16)tanh_fast(accA[jn][2]), (f16)tanh_fast(accA[jn][3]) }; \
        *(f16x4*)(&h1f[(PR)][wroff[jn]]) = t1v; \
        f16x4 t2v = { (f16)tanh_fast(accB[jn][0]), (f16)tanh_fast(accB[jn][1]), \
                      (f16)tanh_fast(accB[jn][2]), (f16)tanh_fast(accB[jn][3]) }; \
        *(f16x4*)(&h2f[(PR)^1][wroff[jn]]) = t2v; \
    } \
    wg_barrier(); \
}

    // --- peeled i = 0: h1[0] = tanh(pre[0] + Whh0 . 0); NO h2 write ---
    {
        f32x4 accA[2];
        #pragma unroll
        for (int jn = 0; jn < 2; jn++)
            #pragma unroll
            for (int r = 0; r < 4; r++) accA[jn][r] = pn[jn * 4 + r];
        #pragma unroll
        for (int jn = 0; jn < 2; jn++)
            #pragma unroll
            for (int r = 0; r < 4; r++)
                pn[jn * 4 + r] = preT[(size_t)1 * (Hn * Bsz) + pbase[jn] + r * Bsz];
        #pragma unroll
        for (int kk = 0; kk < 8; kk++) {
            f16x8 hb1 = *(const f16x8*)(&h1f[1][kk * 512 + lane * 8]);  // zeros
            accA[0] = __builtin_amdgcn_mfma_f32_16x16x32_f16(wh0[0][kk], hb1, accA[0], 0, 0, 0);
            accA[1] = __builtin_amdgcn_mfma_f32_16x16x32_f16(wh0[1][kk], hb1, accA[1], 0, 0, 0);
        }
        #pragma unroll
        for (int jn = 0; jn < 2; jn++) {
            f16x4 t1v = { (f16)tanh_fast(accA[jn][0]), (f16)tanh_fast(accA[jn][1]),
                          (f16)tanh_fast(accA[jn][2]), (f16)tanh_fast(accA[jn][3]) };
            *(f16x4*)(&h1f[0][wroff[jn]]) = t1v;
        }
        wg_barrier();
    }

    // --- steady state: i = 1..1022, branch-free ---
    #pragma unroll 1
    for (int tp = 0; tp < 511; ++tp) {
        const int t1 = 2 * tp + 1;
        FSTEP_FULL(1, t1, (t1 + 1))
        FSTEP_FULL(0, (t1 + 1), (t1 + 2))
    }
    // --- peeled i = 1023 (prefetch target clamped; pn unused afterwards) ---
    FSTEP_FULL(1, 1023, 1023)
#undef FSTEP_FULL

    // --- peeled i = 1024: h2[1023] = tanh(b1 + Wxh1.h1[1023] + Whh1.h2[1022])
    {
        f32x4 accB[2];
        #pragma unroll
        for (int jn = 0; jn < 2; jn++)
            accB[jn] = (f32x4){bi[jn].x, bi[jn].y, bi[jn].z, bi[jn].w};
        #pragma unroll
        for (int kk = 0; kk < 8; kk++) {
            f16x8 hb1 = *(const f16x8*)(&h1f[1][kk * 512 + lane * 8]);  // h1[1023]
            f16x8 hb2 = *(const f16x8*)(&h2f[0][kk * 512 + lane * 8]);  // h2[1022]
            accB[0] = __builtin_amdgcn_mfma_f32_16x16x32_f16(wx [0][kk], hb1, accB[0], 0, 0, 0);
            accB[1] = __builtin_amdgcn_mfma_f32_16x16x32_f16(wx [1][kk], hb1, accB[1], 0, 0, 0);
            accB[0] = __builtin_amdgcn_mfma_f32_16x16x32_f16(wh1[0][kk], hb2, accB[0], 0, 0, 0);
            accB[1] = __builtin_amdgcn_mfma_f32_16x16x32_f16(wh1[1][kk], hb2, accB[1], 0, 0, 0);
        }
        #pragma unroll
        for (int jn = 0; jn < 2; jn++) {
            f16x4 t2v = { (f16)tanh_fast(accB[jn][0]), (f16)tanh_fast(accB[jn][1]),
                          (f16)tanh_fast(accB[jn][2]), (f16)tanh_fast(accB[jn][3]) };
            *(f16x4*)(&h2f[1][wroff[jn]]) = t2v;
        }
        wg_barrier();
    }

    // head: final h2 = h2[1023] in h2f[1]; frag-major.
    if (tid < 256) {
        const int bl = tid >> 4, o = (tid >> 3) & 1, kc = tid & 7;
        float s = 0.f;
        #pragma unroll
        for (int kq = 0; kq < 32; kq++) {
            int k = kc * 32 + kq;
            f16 hv = h2f[1][(k >> 5) * 512 + ((k >> 3) & 3) * 128 + bl * 8 + (k & 7)];
            s += (float)hv * fcw[o * Hn + k];
        }
        s += __shfl_down(s, 4);
        s += __shfl_down(s, 2);
        s += __shfl_down(s, 1);
        if (kc == 0)
            out[(bg + bl) * 2 + o] = s + fcb[o];
    }
}

extern "C" void kernel_launch(void* const* d_in, const int* in_sizes, int n_in,
                              void* d_out, int out_size, void* d_ws, size_t ws_size,
                              hipStream_t stream) {
    const float* x    = (const float*)d_in[0];
    const float* Wxh0 = (const float*)d_in[1];
    const float* Whh0 = (const float*)d_in[2];
    const float* b0   = (const float*)d_in[3];
    const float* Wxh1 = (const float*)d_in[4];
    const float* Whh1 = (const float*)d_in[5];
    const float* b1   = (const float*)d_in[6];
    const float* fcw  = (const float*)d_in[7];
    const float* fcb  = (const float*)d_in[8];
    float* out = (float*)d_out;

    float* preT = (float*)d_ws;  // pre_T[t][j][b] fp32 = 128 MiB

    k_xproj<<<dim3(Tn),       dim3(256), 0, stream>>>(x, Wxh0, b0, preT);
    k_fused<<<dim3(Bsz / 16), dim3(512), 0, stream>>>(Whh0, Wxh1, Whh1, b1,
                                                      fcw, fcb, preT, out);
}

// Round 3
// 1372.193 us; speedup vs baseline: 1.2396x; 1.0478x over previous
//
#include <hip/hip_runtime.h>

#define Bsz 128
#define Tn  1024
#define Dn  256
#define Hn  256

typedef _Float16 f16;
typedef _Float16 f16x4 __attribute__((ext_vector_type(4)));
typedef _Float16 f16x8 __attribute__((ext_vector_type(8)));
typedef float f32x4 __attribute__((ext_vector_type(4)));

// Exact tanh: 1 - 2/(e^{2x}+1) via v_exp_f32. err ~1e-6, saturates correctly.
__device__ __forceinline__ float tanh_fast(float x) {
    float e = __builtin_amdgcn_exp2f(x * 2.88539008177793f);  // e^{2x}
    return 1.0f - 2.0f * __builtin_amdgcn_rcpf(e + 1.0f);
}

// LDS-only barrier (lgkmcnt drain, no vmcnt) so global prefetch loads stay
// in flight across steps. All global loads are consumed by the issuing lane.
__device__ __forceinline__ void wg_barrier() {
    asm volatile("s_waitcnt lgkmcnt(0)\n\ts_barrier" ::: "memory");
}

// h fragment-major LDS layout: element (m=batch 0..15, k=0..255) lives at
// f16 offset (k>>5)*512 + ((k>>3)&3)*128 + m*8 + (k&7).
// A wave's B-fragment read for K-block kk is then ds_read_b128 at
// kk*1024B + lane*16B  -> stride-1 lane-contiguous, conflict-free.

// ---------------------------------------------------------------------------
// K1: pre[t][b][j] = x[b][t][:] . Wxh0[j][:] + b0[j]   (fp32 in/out)
// Transposed GEMM: A = Wxh0 (j rows, regs), B = x_t (b cols, LDS).
// grid = Tn WGs (one t each), 256 thr (4 waves x 64 j-cols).
// OUTPUT LAYOUT [t][b][j]: k_fused's per-lane prefetch (4 consecutive j for
// fixed b) becomes a float4 load; epilogue here becomes float4 stores.
// ---------------------------------------------------------------------------
__global__ __launch_bounds__(256, 2) void k_xproj(
    const float* __restrict__ x, const float* __restrict__ W,
    const float* __restrict__ bias, float* __restrict__ preT)
{
    __shared__ __align__(16) f16 xt[128][264];
    const int tid = threadIdx.x;
    const int t = blockIdx.x;

    // stage x[:, t, :] -> f16 LDS (row-major, padded)
    for (int i = tid; i < 128 * 64; i += 256) {
        int row = i >> 6, c4 = i & 63;
        float4 v = *(const float4*)(x + ((size_t)row * Tn + t) * Dn + c4 * 4);
        f16x4 tv = { (f16)v.x, (f16)v.y, (f16)v.z, (f16)v.w };
        *(f16x4*)(&xt[row][c4 * 4]) = tv;
    }

    const int lane = tid & 63, l15 = lane & 15, quad = lane >> 4;
    const int w = tid >> 6;

    // A-fragments of Wxh0 (j = w*64 + jn*16 + l15, k = kk*32 + quad*8 + e)
    f16x8 wf[4][8];
    #pragma unroll
    for (int jn = 0; jn < 4; jn++) {
        int j = w * 64 + jn * 16 + l15;
        #pragma unroll
        for (int kk = 0; kk < 8; kk++)
            #pragma unroll
            for (int e = 0; e < 8; e++)
                wf[jn][kk][e] = (f16)W[(size_t)j * Dn + kk * 32 + quad * 8 + e];
    }
    float4 bi[4];
    #pragma unroll
    for (int jn = 0; jn < 4; jn++)
        bi[jn] = *(const float4*)(bias + w * 64 + jn * 16 + quad * 4);

    __syncthreads();

    #pragma unroll 1
    for (int bblk = 0; bblk < 8; bblk++) {
        f32x4 acc[4];
        #pragma unroll
        for (int jn = 0; jn < 4; jn++)
            acc[jn] = (f32x4){bi[jn].x, bi[jn].y, bi[jn].z, bi[jn].w};
        #pragma unroll
        for (int kk = 0; kk < 8; kk++) {
            f16x8 xb = *(const f16x8*)(&xt[bblk * 16 + l15][kk * 32 + quad * 8]);
            #pragma unroll
            for (int jn = 0; jn < 4; jn++)
                acc[jn] = __builtin_amdgcn_mfma_f32_16x16x32_f16(wf[jn][kk], xb, acc[jn], 0, 0, 0);
        }
        // C-layout: lane holds rows j = w*64+jn*16+quad*4+r, col b = bblk*16+l15
        // store [t][b][j]: 4 consecutive j per jn -> float4
        #pragma unroll
        for (int jn = 0; jn < 4; jn++) {
            int j0 = w * 64 + jn * 16 + quad * 4;
            *(f32x4*)(preT + ((size_t)t * Bsz + bblk * 16 + l15) * Hn + j0) = acc[jn];
        }
    }
}

// ---------------------------------------------------------------------------
// K2 (fused, LAYER-PIPELINED, tail-hoisted): layer 2 lags layer 1 by one
// step; each iteration i does, per wave (32 j-cols of BOTH layers), with ONE
// barrier:
//   h1[i]   = tanh(pre[i] + Whh0 . h1[i-1])                  (accA, 2x 8-deep)
//   h2[i-1] = tanh(b1 + Wxh1 . h1[i-1] + Whh1 . h2[i-2])     (accB, 2x 16-deep)
// The h1 tail (tanh + ds_write) is placed BETWEEN the accA and accB MFMA
// blocks so it schedules into the accB MFMA shadow; only the h2 tail remains
// serial before the barrier. hb1 fragments are kept in registers across both
// blocks (shared read). i=0 / i=1023 / i=1024 are PEELED (branch-free loop;
// r1's in-loop branches caused scratch spills).
// Parity: h1[i] in h1f[i&1], h2[i] in h2f[i&1].
// 8 WGs x 512 thr; weights (Whh0, Wxh1, Whh1) as A-fragments in registers.
// ---------------------------------------------------------------------------
__global__ __launch_bounds__(512, 1) void k_fused(
    const float* __restrict__ Whh0, const float* __restrict__ Wxh1,
    const float* __restrict__ Whh1, const float* __restrict__ b1v,
    const float* __restrict__ fcw,  const float* __restrict__ fcb,
    const float* __restrict__ preT, float* __restrict__ out)
{
    __shared__ __align__(16) f16 h1f[2][4096];  // 8 KB each, frag-major
    __shared__ __align__(16) f16 h2f[2][4096];

    const int tid  = threadIdx.x;
    const int lane = tid & 63, l15 = lane & 15, quad = lane >> 4;
    const int w    = tid >> 6;
    const int colbase = w * 32;
    const int bg   = blockIdx.x * 16;

    for (int i = tid; i < 4096; i += 512) {
        h1f[0][i] = (f16)0.0f; h1f[1][i] = (f16)0.0f;
        h2f[0][i] = (f16)0.0f; h2f[1][i] = (f16)0.0f;
    }

    // A-fragments: row j = colbase + jn*16 + l15, k = kk*32 + quad*8 + e
    f16x8 wh0[2][8], wx[2][8], wh1[2][8];
    #pragma unroll
    for (int jn = 0; jn < 2; jn++) {
        int j = colbase + jn * 16 + l15;
        #pragma unroll
        for (int kk = 0; kk < 8; kk++)
            #pragma unroll
            for (int e = 0; e < 8; e++) {
                int o = (int)((size_t)j * Hn + kk * 32 + quad * 8 + e);
                wh0[jn][kk][e] = (f16)Whh0[o];
                wx [jn][kk][e] = (f16)Wxh1[o];
                wh1[jn][kk][e] = (f16)Whh1[o];
            }
    }
    float4 bi[2];
    #pragma unroll
    for (int jn = 0; jn < 2; jn++)
        bi[jn] = *(const float4*)(b1v + colbase + jn * 16 + quad * 4);

    // write offsets for the h epilogue (per jn): 4 consecutive k = n0..n0+3
    int wroff[2];
    #pragma unroll
    for (int jn = 0; jn < 2; jn++) {
        int n0 = colbase + jn * 16 + quad * 4;
        wroff[jn] = (n0 >> 5) * 512 + ((n0 >> 3) & 3) * 128 + l15 * 8 + (n0 & 7);
    }

    // prefetch pointer: pre[t][bg+l15][colbase + jn*16 + quad*4 + r]
    //   = pp[ t*Bsz*Hn + jn*16 + r ]   (float4 per jn)
    const float* pp = preT + ((size_t)(bg + l15)) * Hn + colbase + quad * 4;

    // pn holds pre[t] (as 2x float4) at entry to step t
    f32x4 pnv[2];
    pnv[0] = *(const f32x4*)(pp);
    pnv[1] = *(const f32x4*)(pp + 16);
    __syncthreads();

// Steady-state pipelined step, NO branches. PR = I&1 (compile-time).
// Reads h1[i-1] from h1f[PR^1], h2[i-2] from h2f[PR];
// writes h1[i] -> h1f[PR], h2[i-1] -> h2f[PR^1]. Prefetches pre[TF].
#define FSTEP_FULL(PR, I, TF) { \
    f32x4 accA[2]; \
    accA[0] = pnv[0]; accA[1] = pnv[1]; \
    pnv[0] = *(const f32x4*)(pp + (size_t)(TF) * (Bsz * Hn)); \
    pnv[1] = *(const f32x4*)(pp + (size_t)(TF) * (Bsz * Hn) + 16); \
    f16x8 hb1[8]; \
    _Pragma("unroll") for (int kk = 0; kk < 8; kk++) { \
        hb1[kk] = *(const f16x8*)(&h1f[(PR)^1][kk * 512 + lane * 8]); \
        accA[0] = __builtin_amdgcn_mfma_f32_16x16x32_f16(wh0[0][kk], hb1[kk], accA[0], 0, 0, 0); \
        accA[1] = __builtin_amdgcn_mfma_f32_16x16x32_f16(wh0[1][kk], hb1[kk], accA[1], 0, 0, 0); \
    } \
    /* h1 tail here: schedules into the accB MFMA shadow */ \
    _Pragma("unroll") for (int jn = 0; jn < 2; jn++) { \
        f16x4 t1v = { (f16)tanh_fast(accA[jn][0]), (f16)tanh_fast(accA[jn][1]), \
                      (f16)tanh_fast(accA[jn][2]), (f16)tanh_fast(accA[jn][3]) }; \
        *(f16x4*)(&h1f[(PR)][wroff[jn]]) = t1v; \
    } \
    f32x4 accB[2]; \
    _Pragma("unroll") for (int jn = 0; jn < 2; jn++) \
        accB[jn] = (f32x4){bi[jn].x, bi[jn].y, bi[jn].z, bi[jn].w}; \
    _Pragma("unroll") for (int kk = 0; kk < 8; kk++) { \
        f16x8 hb2 = *(const f16x8*)(&h2f[(PR)][kk * 512 + lane * 8]); \
        accB[0] = __builtin_amdgcn_mfma_f32_16x16x32_f16(wx [0][kk], hb1[kk], accB[0], 0, 0, 0); \
        accB[1] = __builtin_amdgcn_mfma_f32_16x16x32_f16(wx [1][kk], hb1[kk], accB[1], 0, 0, 0); \
        accB[0] = __builtin_amdgcn_mfma_f32_16x16x32_f16(wh1[0][kk], hb2, accB[0], 0, 0, 0); \
        accB[1] = __builtin_amdgcn_mfma_f32_16x16x32_f16(wh1[1][kk], hb2, accB[1], 0, 0, 0); \
    } \
    _Pragma("unroll") for (int jn = 0; jn < 2; jn++) { \
        f16x4 t2v = { (f16)tanh_fast(accB[jn][0]), (f16)tanh_fast(accB[jn][1]), \
                      (f16)tanh_fast(accB[jn][2]), (f16)tanh_fast(accB[jn][3]) }; \
        *(f16x4*)(&h2f[(PR)^1][wroff[jn]]) = t2v; \
    } \
    wg_barrier(); \
}

    // --- peeled i = 0: h1[0] = tanh(pre[0] + Whh0 . 0); NO h2 write ---
    {
        f32x4 accA[2];
        accA[0] = pnv[0]; accA[1] = pnv[1];
        pnv[0] = *(const f32x4*)(pp + (size_t)1 * (Bsz * Hn));
        pnv[1] = *(const f32x4*)(pp + (size_t)1 * (Bsz * Hn) + 16);
        #pragma unroll
        for (int kk = 0; kk < 8; kk++) {
            f16x8 hb1 = *(const f16x8*)(&h1f[1][kk * 512 + lane * 8]);  // zeros
            accA[0] = __builtin_amdgcn_mfma_f32_16x16x32_f16(wh0[0][kk], hb1, accA[0], 0, 0, 0);
            accA[1] = __builtin_amdgcn_mfma_f32_16x16x32_f16(wh0[1][kk], hb1, accA[1], 0, 0, 0);
        }
        #pragma unroll
        for (int jn = 0; jn < 2; jn++) {
            f16x4 t1v = { (f16)tanh_fast(accA[jn][0]), (f16)tanh_fast(accA[jn][1]),
                          (f16)tanh_fast(accA[jn][2]), (f16)tanh_fast(accA[jn][3]) };
            *(f16x4*)(&h1f[0][wroff[jn]]) = t1v;
        }
        wg_barrier();
    }

    // --- steady state: i = 1..1022, branch-free ---
    #pragma unroll 1
    for (int tp = 0; tp < 511; ++tp) {
        const int t1 = 2 * tp + 1;
        FSTEP_FULL(1, t1, (t1 + 1))
        FSTEP_FULL(0, (t1 + 1), (t1 + 2))
    }
    // --- peeled i = 1023 (prefetch target clamped; pn unused afterwards) ---
    FSTEP_FULL(1, 1023, 1023)
#undef FSTEP_FULL

    // --- peeled i = 1024: h2[1023] = tanh(b1 + Wxh1.h1[1023] + Whh1.h2[1022])
    {
        f32x4 accB[2];
        #pragma unroll
        for (int jn = 0; jn < 2; jn++)
            accB[jn] = (f32x4){bi[jn].x, bi[jn].y, bi[jn].z, bi[jn].w};
        #pragma unroll
        for (int kk = 0; kk < 8; kk++) {
            f16x8 hb1 = *(const f16x8*)(&h1f[1][kk * 512 + lane * 8]);  // h1[1023]
            f16x8 hb2 = *(const f16x8*)(&h2f[0][kk * 512 + lane * 8]);  // h2[1022]
            accB[0] = __builtin_amdgcn_mfma_f32_16x16x32_f16(wx [0][kk], hb1, accB[0], 0, 0, 0);
            accB[1] = __builtin_amdgcn_mfma_f32_16x16x32_f16(wx [1][kk], hb1, accB[1], 0, 0, 0);
            accB[0] = __builtin_amdgcn_mfma_f32_16x16x32_f16(wh1[0][kk], hb2, accB[0], 0, 0, 0);
            accB[1] = __builtin_amdgcn_mfma_f32_16x16x32_f16(wh1[1][kk], hb2, accB[1], 0, 0, 0);
        }
        #pragma unroll
        for (int jn = 0; jn < 2; jn++) {
            f16x4 t2v = { (f16)tanh_fast(accB[jn][0]), (f16)tanh_fast(accB[jn][1]),
                          (f16)tanh_fast(accB[jn][2]), (f16)tanh_fast(accB[jn][3]) };
            *(f16x4*)(&h2f[1][wroff[jn]]) = t2v;
        }
        wg_barrier();
    }

    // head: final h2 = h2[1023] in h2f[1]; frag-major.
    if (tid < 256) {
        const int bl = tid >> 4, o = (tid >> 3) & 1, kc = tid & 7;
        float s = 0.f;
        #pragma unroll
        for (int kq = 0; kq < 32; kq++) {
            int k = kc * 32 + kq;
            f16 hv = h2f[1][(k >> 5) * 512 + ((k >> 3) & 3) * 128 + bl * 8 + (k & 7)];
            s += (float)hv * fcw[o * Hn + k];
        }
        s += __shfl_down(s, 4);
        s += __shfl_down(s, 2);
        s += __shfl_down(s, 1);
        if (kc == 0)
            out[(bg + bl) * 2 + o] = s + fcb[o];
    }
}

extern "C" void kernel_launch(void* const* d_in, const int* in_sizes, int n_in,
                              void* d_out, int out_size, void* d_ws, size_t ws_size,
                              hipStream_t stream) {
    const float* x    = (const float*)d_in[0];
    const float* Wxh0 = (const float*)d_in[1];
    const float* Whh0 = (const float*)d_in[2];
    const float* b0   = (const float*)d_in[3];
    const float* Wxh1 = (const float*)d_in[4];
    const float* Whh1 = (const float*)d_in[5];
    const float* b1   = (const float*)d_in[6];
    const float* fcw  = (const float*)d_in[7];
    const float* fcb  = (const float*)d_in[8];
    float* out = (float*)d_out;

    float* preT = (float*)d_ws;  // pre[t][b][j] fp32 = 128 MiB

    k_xproj<<<dim3(Tn),       dim3(256), 0, stream>>>(x, Wxh0, b0, preT);
    k_fused<<<dim3(Bsz / 16), dim3(512), 0, stream>>>(Whh0, Wxh1, Whh1, b1,
                                                      fcw, fcb, preT, out);
}